// Round 2
// baseline (7324.710 us; speedup 1.0000x reference)
//
#include <hip/hip_runtime.h>
#include <math.h>

#define Hh 240
#define Ww 480
#define HW 115200      // Hh*Ww
#define Cc 128
#define Kk 1152        // Cc*9
#define HALFW 240      // Ww/2
#define NB_RED 1440

// ---------------------------------------------------------------------------
// geo_pad-fused fetch: value of geo_pad(x,1) at padded coords, expressed via
// unpadded (r,c) with r in [-1,Hh], c in [-1,Ww].
// ---------------------------------------------------------------------------
__device__ __forceinline__ float geo_fetch(const float* __restrict__ base, int ch, int r, int c) {
    int wv = (c < 0) ? (Ww - 1) : ((c >= Ww) ? 0 : c);
    int rr;
    if (r < 0)        { rr = 0;      wv = (wv >= HALFW) ? wv - HALFW : wv + HALFW; }
    else if (r >= Hh) { rr = Hh - 1; wv = (wv >= HALFW) ? wv - HALFW : wv + HALFW; }
    else              { rr = r; }
    return base[(ch * Hh + rr) * Ww + wv];
}

__device__ __forceinline__ float padfetch(const float* __restrict__ p, int yi, int xj) {
    int r = yi - 1, c = xj - 1;
    int wv = (c < 0) ? (Ww - 1) : ((c >= Ww) ? 0 : c);
    int rr;
    if (r < 0)        { rr = 0;      wv = (wv >= HALFW) ? wv - HALFW : wv + HALFW; }
    else if (r >= Hh) { rr = Hh - 1; wv = (wv >= HALFW) ? wv - HALFW : wv + HALFW; }
    else              { rr = r; }
    return p[rr * Ww + wv];
}

// small-angle double sincos (|x| <~ 0.7), libm fallback
__device__ __forceinline__ void sincos_small(double x, double* s, double* c) {
    double x2 = x * x;
    if (x2 > 0.49) { *s = sin(x); *c = cos(x); return; }
    *s = x * (1.0 + x2 * (-1.6666666666666666e-1 + x2 * (8.3333333333333333e-3 +
         x2 * (-1.9841269841269841e-4 + x2 * (2.7557319223985893e-6 - x2 * 2.5052108385441720e-8)))));
    *c = 1.0 + x2 * (-0.5 + x2 * (4.1666666666666666e-2 + x2 * (-1.3888888888888889e-3 +
         x2 * (2.4801587301587302e-5 - x2 * 2.7557319223985893e-7))));
}

// ---------------------------------------------------------------------------
__global__ void transpose_w(const float* __restrict__ w, float* __restrict__ wT, int N) {
    int idx = blockIdx.x * 256 + threadIdx.x;      // idx = k*N + n
    if (idx >= N * Kk) return;
    int k = idx / N;
    int n = idx - k * N;
    wT[idx] = w[n * Kk + k];
}

// ---------------------------------------------------------------------------
// implicit-GEMM 3x3 conv, geo_pad fused into the gather.
// 128x128 tile, BK=32, 256 threads, 8x8 micro-tile (split 4+4).
// ---------------------------------------------------------------------------
__global__ __launch_bounds__(256)
void conv_gemm(const float* __restrict__ in,    // [Cc][HW] batch plane base
               const float* __restrict__ wT,    // [Kk][N]
               const float* __restrict__ bias,  // [N]
               float* __restrict__ out,         // [N][HW]
               int N)
{
    const int tid = threadIdx.x;
    const int tx = tid & 15;     // m
    const int ty = tid >> 4;     // n
    const int m0 = blockIdx.x * 128;
    const int n0 = blockIdx.y * 128;

    __shared__ float As[32][128];  // [k][m]
    __shared__ float Bs[32][128];  // [k][n]

    float acc[8][8] = {};

    for (int kt = 0; kt < Kk; kt += 32) {
        #pragma unroll
        for (int i = 0; i < 16; i++) {
            int l  = tid + i * 256;
            int mi = l & 127;
            int ki = l >> 7;
            int m  = m0 + mi;
            int k  = kt + ki;
            int h  = m / Ww;
            int w  = m - h * Ww;
            int ic = k / 9;
            int t9 = k - ic * 9;
            int kh = t9 / 3;
            int kw = t9 - kh * 3;
            As[ki][mi] = geo_fetch(in, ic, h + kh - 1, w + kw - 1);
        }
        #pragma unroll
        for (int i = 0; i < 16; i++) {
            int l  = tid + i * 256;
            int ni = l & 127;
            int ki = l >> 7;
            Bs[ki][ni] = wT[(kt + ki) * N + n0 + ni];
        }
        __syncthreads();
        #pragma unroll
        for (int kk = 0; kk < 32; kk++) {
            float4 a0 = *(const float4*)&As[kk][tx * 4];
            float4 a1 = *(const float4*)&As[kk][64 + tx * 4];
            float4 b0 = *(const float4*)&Bs[kk][ty * 4];
            float4 b1 = *(const float4*)&Bs[kk][64 + ty * 4];
            float av[8] = {a0.x, a0.y, a0.z, a0.w, a1.x, a1.y, a1.z, a1.w};
            float bv[8] = {b0.x, b0.y, b0.z, b0.w, b1.x, b1.y, b1.z, b1.w};
            #pragma unroll
            for (int i = 0; i < 8; i++)
                #pragma unroll
                for (int j = 0; j < 8; j++)
                    acc[i][j] = fmaf(av[i], bv[j], acc[i][j]);
        }
        __syncthreads();
    }

    #pragma unroll
    for (int hn = 0; hn < 2; hn++)
        #pragma unroll
        for (int j = 0; j < 4; j++) {
            int n = n0 + hn * 64 + ty * 4 + j;
            float bv = bias[n];
            #pragma unroll
            for (int hm = 0; hm < 2; hm++) {
                float4 o;
                o.x = acc[hm * 4 + 0][hn * 4 + j] + bv;
                o.y = acc[hm * 4 + 1][hn * 4 + j] + bv;
                o.z = acc[hm * 4 + 2][hn * 4 + j] + bv;
                o.w = acc[hm * 4 + 3][hn * 4 + j] + bv;
                *(float4*)&out[(size_t)n * HW + m0 + hm * 64 + tx * 4] = o;
            }
        }
}

// ---------------------------------------------------------------------------
// deterministic two-stage LayerNorm stats
// ---------------------------------------------------------------------------
__global__ __launch_bounds__(256)
void reduce_stats(const float* __restrict__ y, float* __restrict__ part) {
    const int n4 = (Cc * HW) / 4;
    float s = 0.f, ss = 0.f;
    for (int i = blockIdx.x * 256 + threadIdx.x; i < n4; i += NB_RED * 256) {
        float4 v = ((const float4*)y)[i];
        s  += v.x + v.y + v.z + v.w;
        ss += v.x * v.x + v.y * v.y + v.z * v.z + v.w * v.w;
    }
    #pragma unroll
    for (int o = 32; o > 0; o >>= 1) { s += __shfl_down(s, o); ss += __shfl_down(ss, o); }
    __shared__ float ls[4], lss[4];
    int wid = threadIdx.x >> 6, lane = threadIdx.x & 63;
    if (lane == 0) { ls[wid] = s; lss[wid] = ss; }
    __syncthreads();
    if (threadIdx.x == 0) {
        part[blockIdx.x * 2]     = ls[0] + ls[1] + ls[2] + ls[3];
        part[blockIdx.x * 2 + 1] = lss[0] + lss[1] + lss[2] + lss[3];
    }
}

__global__ __launch_bounds__(256)
void finalize_stats(const float* __restrict__ part, float* __restrict__ stats) {
    float s = 0.f, ss = 0.f;
    for (int i = threadIdx.x; i < NB_RED; i += 256) { s += part[2 * i]; ss += part[2 * i + 1]; }
    #pragma unroll
    for (int o = 32; o > 0; o >>= 1) { s += __shfl_down(s, o); ss += __shfl_down(ss, o); }
    __shared__ float ls[4], lss[4];
    int wid = threadIdx.x >> 6, lane = threadIdx.x & 63;
    if (lane == 0) { ls[wid] = s; lss[wid] = ss; }
    __syncthreads();
    if (threadIdx.x == 0) {
        stats[0] = ls[0] + ls[1] + ls[2] + ls[3];
        stats[1] = lss[0] + lss[1] + lss[2] + lss[3];
    }
}

__global__ void norm_silu(float* __restrict__ y, const float* __restrict__ g,
                          const float* __restrict__ bb, const float* __restrict__ stats) {
    int i = blockIdx.x * 256 + threadIdx.x;
    if (i >= Cc * HW) return;
    const float invN = 1.f / (float)(Cc * HW);
    float mu  = stats[0] * invN;
    float var = stats[1] * invN - mu * mu;
    float inv = rsqrtf(var + 1e-5f);
    float z = (y[i] - mu) * inv * g[i] + bb[i];
    y[i] = z / (1.f + expf(-z));
}

// ---------------------------------------------------------------------------
// per-pixel sin/cos(lat) in double, once per batch
// ---------------------------------------------------------------------------
__global__ void pix_trig(const float* __restrict__ latg, double* __restrict__ sphid) {
    int m = blockIdx.x * 256 + threadIdx.x;
    if (m >= HW) return;
    double phi = (double)latg[m];
    sphid[m]      = sin(phi);
    sphid[HW + m] = cos(phi);
}

// ---------------------------------------------------------------------------
// departure-point trig (fp64) + bicubic sample of geo-padded original input
// ---------------------------------------------------------------------------
__global__ __launch_bounds__(256)
void semilag(const float* __restrict__ vel,     // [2*Cc][HW] batch base
             const float* __restrict__ hid,     // [Cc][HW] batch base
             const double* __restrict__ sphid,  // [2][HW] sin/cos(lat)
             const float* __restrict__ lng,     // [HW]
             const float* __restrict__ dtp,
             float* __restrict__ out)           // [Cc][HW] batch base
{
    int idx = blockIdx.x * 256 + threadIdx.x;
    if (idx >= Cc * HW) return;
    int c = idx / HW;
    int m = idx - c * HW;

    const double TWO_PI = 6.2831853071795864769252867665590;
    const double PI_D   = 3.1415926535897932384626433832795;

    double dt = (double)dtp[0];
    double u = (double)vel[idx];
    double v = (double)vel[Cc * HW + idx];
    double lonp = -u * dt, latp = -v * dt;

    double slp, clp, slo, clo;
    sincos_small(latp, &slp, &clp);
    sincos_small(lonp, &slo, &clo);
    double sphi = sphid[m], cphi = sphid[HW + m];

    double sinlat = slp * cphi + clp * clo * sphi;
    sinlat = fmin(fmax(sinlat, -1.0 + 1e-7), 1.0 - 1e-7);
    double lat_dep = asin(sinlat);

    double num = clp * slo;
    double den = clp * clo * cphi - slp * sphi;
    double lon_dep = (double)lng[m] + atan2(num, den);
    double xr = lon_dep + TWO_PI;
    xr = xr - floor(xr / TWO_PI) * TWO_PI;

    double gx = (xr / TWO_PI * 2.0 - 1.0) * (480.0 / 482.0);
    double gy = (lat_dep / PI_D * 2.0 - 1.0) * (240.0 / 242.0);

    double ixd = fmin(fmax((gx + 1.0) * 0.5 * 481.0, 0.0), 481.0);
    double iyd = fmin(fmax((gy + 1.0) * 0.5 * 241.0, 0.0), 241.0);
    double x0d = floor(ixd), y0d = floor(iyd);
    float fx = (float)(ixd - x0d), fy = (float)(iyd - y0d);
    int x0 = (int)x0d, y0 = (int)y0d;

    const float a = -0.75f;
    float wx[4], wy[4];
    {
        float t = fx;
        float t1 = 1.f + t, t2 = 2.f - t, s1 = 1.f - t;
        wx[0] = ((a * t1 - 5.f * a) * t1 + 8.f * a) * t1 - 4.f * a;
        wx[1] = ((a + 2.f) * t - (a + 3.f)) * t * t + 1.f;
        wx[2] = ((a + 2.f) * s1 - (a + 3.f)) * s1 * s1 + 1.f;
        wx[3] = ((a * t2 - 5.f * a) * t2 + 8.f * a) * t2 - 4.f * a;
        t = fy;
        t1 = 1.f + t; t2 = 2.f - t; s1 = 1.f - t;
        wy[0] = ((a * t1 - 5.f * a) * t1 + 8.f * a) * t1 - 4.f * a;
        wy[1] = ((a + 2.f) * t - (a + 3.f)) * t * t + 1.f;
        wy[2] = ((a + 2.f) * s1 - (a + 3.f)) * s1 * s1 + 1.f;
        wy[3] = ((a * t2 - 5.f * a) * t2 + 8.f * a) * t2 - 4.f * a;
    }

    const float* plane = hid + (size_t)c * HW;
    float accv = 0.f;
    #pragma unroll
    for (int i = 0; i < 4; i++) {
        int yi = min(max(y0 + i - 1, 0), 241);
        float row = 0.f;
        #pragma unroll
        for (int j = 0; j < 4; j++) {
            int xj = min(max(x0 + j - 1, 0), 481);
            row = fmaf(wx[j], padfetch(plane, yi, xj), row);
        }
        accv = fmaf(wy[i], row, accv);
    }
    out[idx] = accv;
}

// ---------------------------------------------------------------------------
extern "C" void kernel_launch(void* const* d_in, const int* in_sizes, int n_in,
                              void* d_out, int out_size, void* d_ws, size_t ws_size,
                              hipStream_t stream)
{
    const float* hidden = (const float*)d_in[0];
    const float* latg   = (const float*)d_in[1];
    const float* lng    = (const float*)d_in[2];
    const float* w1     = (const float*)d_in[3];
    const float* b1     = (const float*)d_in[4];
    const float* g      = (const float*)d_in[5];
    const float* lb     = (const float*)d_in[6];
    const float* w2     = (const float*)d_in[7];
    const float* b2     = (const float*)d_in[8];
    const float* dt     = (const float*)d_in[9];
    float* out = (float*)d_out;

    // ws layout (floats): stats[4] | part[2880] | wT1 | wT2 | y1[C*HW] | vel[2C*HW]
    float* ws    = (float*)d_ws;
    float* stats = ws;
    float* part  = ws + 4;
    float* wT1   = part + 2 * NB_RED;
    float* wT2   = wT1 + Kk * Cc;
    float* y1    = wT2 + Kk * 2 * Cc;
    float* vel   = y1 + (size_t)Cc * HW;
    double* dbuf = (double*)y1;   // y1 region reused after conv2 (8B-aligned)

    transpose_w<<<(Cc * Kk + 255) / 256, 256, 0, stream>>>(w1, wT1, Cc);
    transpose_w<<<(2 * Cc * Kk + 255) / 256, 256, 0, stream>>>(w2, wT2, 2 * Cc);

    for (int b = 0; b < 2; b++) {
        const float* hb = hidden + (size_t)b * Cc * HW;
        conv_gemm<<<dim3(HW / 128, 1), 256, 0, stream>>>(hb, wT1, b1, y1, Cc);
        reduce_stats<<<NB_RED, 256, 0, stream>>>(y1, part);
        finalize_stats<<<1, 256, 0, stream>>>(part, stats + 2 * b);
        norm_silu<<<(Cc * HW) / 256, 256, 0, stream>>>(y1, g, lb, stats + 2 * b);
        conv_gemm<<<dim3(HW / 128, 2), 256, 0, stream>>>(y1, wT2, b2, vel, 2 * Cc);
        pix_trig<<<(HW + 255) / 256, 256, 0, stream>>>(latg + (size_t)b * HW, dbuf);
        semilag<<<(Cc * HW) / 256, 256, 0, stream>>>(vel, hb, dbuf,
                                                     lng + (size_t)b * HW, dt,
                                                     out + (size_t)b * Cc * HW);
    }
}